// Round 4
// baseline (226.205 us; speedup 1.0000x reference)
//
#include <hip/hip_runtime.h>

// ColorHistogramLoss: B=32, C=3, H=W=512, BINS=64.
// loss = mean | hist(input)/N - hist(target)/N | over 96*64 bins.
//
// R4: LDS-free ballot histogram. R1/R2/R3 (three different LDS schemes) all
// pinned at 75us -> DS pipe is the floor (~1 DS wave-instr/pixel). Here lane l
// owns bin l: per 64-pixel slot, 6 bit-plane ballots + per-lane
// popcount( AND_k (B_k ^ inv_k) ) counts this lane's bin occupancy.
// ~40 VALU instrs / 64 pixels on the idle VALU pipe, zero DS ops, one global
// atomic wave-instr per wave. All 16 dwordx4 loads issued upfront (MLP fix).

#define BINS 64
#define PLANES 96          // B*C
#define PLANE_F4 65536     // 512*512/4
#define SEGS 32            // segments per plane
#define SEG_F4 2048        // PLANE_F4/SEGS
#define TPB 256
#define F4T 8              // float4 per thread per tensor

__global__ __launch_bounds__(TPB) void hist_diff_kernel(
        const float4* __restrict__ in4, const float4* __restrict__ tg4,
        int* __restrict__ gdiff) {
    const int tid  = threadIdx.x;
    const int lane = tid & 63;
    const int plane = blockIdx.x >> 5;           // /SEGS
    const int seg   = blockIdx.x & (SEGS - 1);
    const long base = (long)plane * PLANE_F4 + (long)seg * SEG_F4 + tid;

    // inv[k]: all-ones iff bit k of my lane (=my bin) is 0, so
    // (ballot(bit k of bin) ^ inv[k]) has bit j set iff lane j's bin bit k
    // matches mine.
    unsigned long long inv[6];
#pragma unroll
    for (int k = 0; k < 6; ++k)
        inv[k] = ((lane >> k) & 1) ? 0ull : ~0ull;

    float4 a[F4T], b[F4T];
#pragma unroll
    for (int k = 0; k < F4T; ++k) a[k] = in4[base + k * TPB];
#pragma unroll
    for (int k = 0; k < F4T; ++k) b[k] = tg4[base + k * TPB];

    int cin = 0, ctg = 0;
    // one slot = one pixel per lane. bin formula identical to R1-R3 (absmax 0).
    // inputs are in [-1,1) -> x in [0,63): no validity mask needed.
    auto slot = [&](float v, int& cnt) {
        float x = (v + 1.0f) * 31.5f;
        int bin = (int)x;
        bin = bin > 63 ? 63 : bin;               // defensive clamp
        unsigned long long m =
            (__ballot(bin & 1)  ^ inv[0]) &
            (__ballot(bin & 2)  ^ inv[1]) &
            (__ballot(bin & 4)  ^ inv[2]) &
            (__ballot(bin & 8)  ^ inv[3]) &
            (__ballot(bin & 16) ^ inv[4]) &
            (__ballot(bin & 32) ^ inv[5]);
        cnt += __popcll(m);                      // lanes that hit my bin
    };
#pragma unroll
    for (int k = 0; k < F4T; ++k) {
        slot(a[k].x, cin); slot(a[k].y, cin);
        slot(a[k].z, cin); slot(a[k].w, cin);
    }
#pragma unroll
    for (int k = 0; k < F4T; ++k) {
        slot(b[k].x, ctg); slot(b[k].y, ctg);
        slot(b[k].z, ctg); slot(b[k].w, ctg);
    }

    const int d = cin - ctg;                     // signed diff for my bin
    if (d != 0) atomicAdd(&gdiff[plane * BINS + lane], d);
}

__global__ __launch_bounds__(TPB) void reduce_abs_kernel(
        const int* __restrict__ gdiff, float* __restrict__ out) {
    int s = 0;
    for (int i = threadIdx.x; i < PLANES * BINS; i += TPB) {
        int v = gdiff[i];
        s += (v < 0) ? -v : v;
    }
#pragma unroll
    for (int off = 32; off > 0; off >>= 1) s += __shfl_down(s, off, 64);
    __shared__ int ws[TPB / 64];
    const int wid  = threadIdx.x >> 6;
    const int lane = threadIdx.x & 63;
    if (lane == 0) ws[wid] = s;
    __syncthreads();
    if (threadIdx.x == 0) {
        int total = 0;
#pragma unroll
        for (int w = 0; w < TPB / 64; ++w) total += ws[w];
        out[0] = (float)total * (1.0f / (262144.0f * 6144.0f));
    }
}

extern "C" void kernel_launch(void* const* d_in, const int* in_sizes, int n_in,
                              void* d_out, int out_size, void* d_ws, size_t ws_size,
                              hipStream_t stream) {
    const float4* inp = (const float4*)d_in[0];
    const float4* tgt = (const float4*)d_in[1];
    int* gdiff = (int*)d_ws;   // 96*64 signed counts, 24 KiB

    hipMemsetAsync(gdiff, 0, PLANES * BINS * sizeof(int), stream);
    hist_diff_kernel<<<PLANES * SEGS, TPB, 0, stream>>>(inp, tgt, gdiff);
    reduce_abs_kernel<<<1, TPB, 0, stream>>>(gdiff, (float*)d_out);
}

// Round 5
// 217.521 us; speedup vs baseline: 1.0399x; 1.0399x over previous
//
#include <hip/hip_runtime.h>

// ColorHistogramLoss: B=32, C=3, H=W=512, BINS=64.
// loss = mean | hist(input)/N - hist(target)/N | over 96*64 bins.
//
// R5: hybrid pipe-split. Measured floors: DS-atomic method = 75us (DS pipe,
// ~58 cyc per ds_add wave-instr, conflict-independent: R1==R2), ballot
// method = 90us (VALU pipe, DS idle). The pipes co-schedule across waves
// (m114). So every block runs BOTH: waves 0-1 DS-atomic on 9/16 of pixels,
// waves 2-3 ballot on 7/16. Balance: 0.91*x = 1.4*(1-x) -> x ~ 0.56 ~ 9/16.
// Expected ~ max(42, 39) ~ 45us.

#define BINS 64
#define PLANES 96          // B*C
#define PLANE_F4 65536     // 512*512/4
#define SEGS 32            // segments per plane
#define SEG_F4 2048        // PLANE_F4/SEGS
#define TPB 256
#define DS_F4 9            // float4 per DS lane per tensor (128 lanes -> 1152)
#define BL_F4 7            // float4 per ballot lane per tensor (128 lanes -> 896)

// bin formula identical to R4 (absmax 0): inputs in [-1,1) -> bin in [0,63],
// only top clamp needed.
__device__ __forceinline__ int binof(float v) {
    float x = (v + 1.0f) * 31.5f;
    int bin = (int)x;
    return bin > 63 ? 63 : bin;
}

__global__ __launch_bounds__(TPB) void hist_diff_kernel(
        const float4* __restrict__ in4, const float4* __restrict__ tg4,
        int* __restrict__ gdiff) {
    __shared__ int lh[BINS];
    const int tid  = threadIdx.x;
    const int plane = blockIdx.x >> 5;           // /SEGS
    const int seg   = blockIdx.x & (SEGS - 1);
    const long segbase = (long)plane * PLANE_F4 + (long)seg * SEG_F4;

    if (tid < BINS) lh[tid] = 0;
    __syncthreads();

    int bdiff = 0;                               // ballot waves' per-bin diff

    if (tid < 128) {
        // ---- DS-atomic method: waves 0-1, float4 indices [0,1152) ----
        const long base = segbase + tid;
        float4 a[DS_F4];
#pragma unroll
        for (int k = 0; k < DS_F4; ++k) a[k] = in4[base + k * 128];
#pragma unroll
        for (int k = 0; k < DS_F4; ++k) {
            atomicAdd(&lh[binof(a[k].x)], 1); atomicAdd(&lh[binof(a[k].y)], 1);
            atomicAdd(&lh[binof(a[k].z)], 1); atomicAdd(&lh[binof(a[k].w)], 1);
        }
#pragma unroll
        for (int k = 0; k < DS_F4; ++k) a[k] = tg4[base + k * 128];
#pragma unroll
        for (int k = 0; k < DS_F4; ++k) {
            atomicAdd(&lh[binof(a[k].x)], -1); atomicAdd(&lh[binof(a[k].y)], -1);
            atomicAdd(&lh[binof(a[k].z)], -1); atomicAdd(&lh[binof(a[k].w)], -1);
        }
    } else {
        // ---- ballot method: waves 2-3, float4 indices [1152,2048) ----
        const int lane = tid & 63;
        unsigned long long inv[6];
#pragma unroll
        for (int k = 0; k < 6; ++k)
            inv[k] = ((lane >> k) & 1) ? 0ull : ~0ull;

        const long base = segbase + 1152 + (tid - 128);
        float4 a[BL_F4], b[BL_F4];
#pragma unroll
        for (int k = 0; k < BL_F4; ++k) a[k] = in4[base + k * 128];
#pragma unroll
        for (int k = 0; k < BL_F4; ++k) b[k] = tg4[base + k * 128];

        int cin = 0, ctg = 0;
        auto slot = [&](float v, int& cnt) {
            int bin = binof(v);
            unsigned long long m =
                (__ballot(bin & 1)  ^ inv[0]) &
                (__ballot(bin & 2)  ^ inv[1]) &
                (__ballot(bin & 4)  ^ inv[2]) &
                (__ballot(bin & 8)  ^ inv[3]) &
                (__ballot(bin & 16) ^ inv[4]) &
                (__ballot(bin & 32) ^ inv[5]);
            cnt += __popcll(m);
        };
#pragma unroll
        for (int k = 0; k < BL_F4; ++k) {
            slot(a[k].x, cin); slot(a[k].y, cin);
            slot(a[k].z, cin); slot(a[k].w, cin);
        }
#pragma unroll
        for (int k = 0; k < BL_F4; ++k) {
            slot(b[k].x, ctg); slot(b[k].y, ctg);
            slot(b[k].z, ctg); slot(b[k].w, ctg);
        }
        bdiff = cin - ctg;
    }

    __syncthreads();
    // merge: wave 0 flushes the LDS hist; ballot waves flush their own counts
    if (tid < BINS) {
        int v = lh[tid];
        if (v != 0) atomicAdd(&gdiff[plane * BINS + tid], v);
    }
    if (tid >= 128 && bdiff != 0)
        atomicAdd(&gdiff[plane * BINS + (tid & 63)], bdiff);
}

__global__ __launch_bounds__(TPB) void reduce_abs_kernel(
        const int* __restrict__ gdiff, float* __restrict__ out) {
    int s = 0;
    for (int i = threadIdx.x; i < PLANES * BINS; i += TPB) {
        int v = gdiff[i];
        s += (v < 0) ? -v : v;
    }
#pragma unroll
    for (int off = 32; off > 0; off >>= 1) s += __shfl_down(s, off, 64);
    __shared__ int ws[TPB / 64];
    const int wid  = threadIdx.x >> 6;
    const int lane = threadIdx.x & 63;
    if (lane == 0) ws[wid] = s;
    __syncthreads();
    if (threadIdx.x == 0) {
        int total = 0;
#pragma unroll
        for (int w = 0; w < TPB / 64; ++w) total += ws[w];
        out[0] = (float)total * (1.0f / (262144.0f * 6144.0f));
    }
}

extern "C" void kernel_launch(void* const* d_in, const int* in_sizes, int n_in,
                              void* d_out, int out_size, void* d_ws, size_t ws_size,
                              hipStream_t stream) {
    const float4* inp = (const float4*)d_in[0];
    const float4* tgt = (const float4*)d_in[1];
    int* gdiff = (int*)d_ws;   // 96*64 signed counts, 24 KiB

    hipMemsetAsync(gdiff, 0, PLANES * BINS * sizeof(int), stream);
    hist_diff_kernel<<<PLANES * SEGS, TPB, 0, stream>>>(inp, tgt, gdiff);
    reduce_abs_kernel<<<1, TPB, 0, stream>>>(gdiff, (float*)d_out);
}